// Round 14
// baseline (435.685 us; speedup 1.0000x reference)
//
#include <hip/hip_runtime.h>
#include <math.h>

// Problem dims (fixed by setup_inputs)
constexpr int L  = 16384;   // 32*32*16 spatial (z=32, y=32, x=16)
constexpr int LC = 64;      // scan chunk length
constexpr int NC = 256;     // L / LC chunks

// padded volume for ELK convs: halo 2 on every side
constexpr int PX = 20, PY = 36, PZ = 36;
constexpr int PSY = PX;            // y stride
constexpr int PSZ = PY*PX;         // z stride = 720
constexpr int PCH = PZ*PSZ;        // channel stride = 25920

// k_elk LDS tile strides (x padded 20->24: tap reads are balanced 2-way banks)
constexpr int TSX = 24;
constexpr int TSZ = 20*TSX;        // 480
constexpr int TILE_N = 5*TSZ;      // 2400

__device__ __forceinline__ float sigm(float x){ return 1.0f/(1.0f+__expf(-x)); }
__device__ __forceinline__ float softplus_(float x){ return (x>20.0f)? x : log1pf(__expf(x)); }

// block-wide {sum, sumsq} accumulation into global via atomics (256-thread blocks)
__device__ __forceinline__ void block_accum2(float s, float s2, float* g0, float* g1){
    #pragma unroll
    for (int m=1;m<64;m<<=1){ s += __shfl_xor(s,m,64); s2 += __shfl_xor(s2,m,64); }
    __shared__ float red[16];
    int lane = threadIdx.x & 63, wid = threadIdx.x >> 6;
    if (lane==0){ red[wid]=s; red[8+wid]=s2; }
    __syncthreads();
    if (threadIdx.x==0){
        int nw = blockDim.x >> 6;
        float a=0.f,b=0.f;
        for (int i=0;i<nw;i++){ a+=red[i]; b+=red[8+i]; }
        atomicAdd(g0,a); atomicAdd(g1,b);
    }
}

// ---------------- Mamba branch ----------------

// LayerNorm over 32 channels + in_proj (32->128), LDS-staged weights.
// grid (L/64, 4), block 256.
__global__ __launch_bounds__(256,2)
void k_ln_proj(const float* __restrict__ x, const float* __restrict__ g,
               const float* __restrict__ b, const float* __restrict__ w,
               float* __restrict__ xi, float* __restrict__ z)
{
    __shared__ float xn[64][33];      // [l][c]
    __shared__ float wt[32][36];      // wt[c][j] = w[(j0b+j)*32+c]
    int t  = threadIdx.x;
    int lq = t>>2, dc = t&3;
    int l  = blockIdx.x*64 + lq;
    int c0 = dc*8;
    int j0b = blockIdx.y*32;

    // stage weights transposed (coalesced reads)
    #pragma unroll
    for (int k=0;k<4;k++){
        int idx = t + k*256;          // 1024 = 32x32
        int j = idx>>5, c = idx&31;
        wt[c][j] = w[(j0b+j)*32+c];
    }

    float xv[8]; float s=0.f, s2=0.f;
    #pragma unroll
    for (int cc=0;cc<8;cc++){
        float v = x[(32+c0+cc)*L + l];
        xv[cc]=v; s+=v; s2+=v*v;
    }
    // quartet butterfly over 2 scalars
    #pragma unroll
    for (int m=1;m<4;m<<=1){ s += __shfl_xor(s,m,64); s2 += __shfl_xor(s2,m,64); }
    float mu  = s*(1.0f/32.0f);
    float var = s2*(1.0f/32.0f) - mu*mu;
    float inv = rsqrtf(var + 1e-5f);
    #pragma unroll
    for (int cc=0;cc<8;cc++)
        xn[lq][c0+cc] = (xv[cc]-mu)*inv*g[c0+cc] + b[c0+cc];
    __syncthreads();

    float acc[8];
    #pragma unroll
    for (int jj=0;jj<8;jj++) acc[jj]=0.f;
    #pragma unroll 4
    for (int c=0;c<32;c++){
        float uv = xn[lq][c];
        float4 w0 = *reinterpret_cast<const float4*>(&wt[c][dc*8]);
        float4 w1 = *reinterpret_cast<const float4*>(&wt[c][dc*8+4]);
        acc[0]+=w0.x*uv; acc[1]+=w0.y*uv; acc[2]+=w0.z*uv; acc[3]+=w0.w*uv;
        acc[4]+=w1.x*uv; acc[5]+=w1.y*uv; acc[6]+=w1.z*uv; acc[7]+=w1.w*uv;
    }
    int j0 = j0b + dc*8;
    if (j0 < 64){
        #pragma unroll
        for (int jj=0;jj<8;jj++) xi[(j0+jj)*L+l] = acc[jj];
    } else {
        #pragma unroll
        for (int q=0;q<2;q++)
            *reinterpret_cast<float4*>(z + l*64 + (j0-64) + q*4) =
                make_float4(acc[q*4], acc[q*4+1], acc[q*4+2], acc[q*4+3]);
    }
}

// depthwise causal conv1d + SiLU + x_proj + dt_proj(softplus), LDS-staged weights.
// grid (L/64, 2), block 256.
__global__ __launch_bounds__(256,2)
void k_conv_proj(const float* __restrict__ xi,
    const float* __restrict__ cwf, const float* __restrict__ cbf,
    const float* __restrict__ xwf, const float* __restrict__ dwf, const float* __restrict__ dbf,
    const float* __restrict__ cwb, const float* __restrict__ cbb,
    const float* __restrict__ xwb, const float* __restrict__ dwb, const float* __restrict__ dbb,
    float* __restrict__ uf, float* __restrict__ dlf, float* __restrict__ Bfp, float* __restrict__ Cfp,
    float* __restrict__ ub, float* __restrict__ dlb, float* __restrict__ Bbp, float* __restrict__ Cbp)
{
    __shared__ float uls[64][65];     // [l][d]
    __shared__ float xwt[64][36];     // xwt[c][r] = xw[r*64+c], r<34 (dt0,dt1,B0-15,C0-15)
    int t  = threadIdx.x;
    int lq = t>>2, dc = t&3;
    int l  = blockIdx.x*64 + lq;
    int d0 = dc*16;
    int gd = blockIdx.y;
    const float* cw = gd? cwb:cwf; const float* cb = gd? cbb:cbf;
    const float* xw = gd? xwb:xwf; const float* dw = gd? dwb:dwf; const float* db = gd? dbb:dbf;
    float* up = gd? ub:uf; float* dp = gd? dlb:dlf;
    float* Bp = gd? Bbp:Bfp; float* Cp = gd? Cbp:Cfp;

    // stage x_proj weights transposed
    #pragma unroll
    for (int k=0;k<9;k++){
        int idx = t + k*256;          // 2176 = 34x64
        if (idx < 34*64){
            int r = idx>>6, c = idx&63;
            xwt[c][r] = xw[idx];
        }
    }

    // phase 1: conv + SiLU for 16 channels
    float u16[16];
    #pragma unroll
    for (int dd=0; dd<16; dd++){
        int d = d0+dd;
        float s = cb[d];
        #pragma unroll
        for (int k=0;k<4;k++){
            int j = l-3+k;                       // position in (possibly reversed) sequence
            float v = 0.0f;
            if (j>=0) v = xi[d*L + (gd ? (L-1-j) : j)];
            s += cw[d*4+k]*v;
        }
        float u = s*sigm(s);                     // SiLU
        u16[dd] = u;
        uls[lq][d] = u;
    }
    #pragma unroll
    for (int q=0;q<4;q++)
        *reinterpret_cast<float4*>(up + l*64 + d0 + q*4) =
            make_float4(u16[q*4], u16[q*4+1], u16[q*4+2], u16[q*4+3]);
    __syncthreads();

    // phase 2: 8 B/C rows per lane + dt (all lanes), from LDS
    float acc[8]; float t0=0.f, t1=0.f;
    #pragma unroll
    for (int jj=0;jj<8;jj++) acc[jj]=0.f;
    int rb = 2 + dc*8;
    #pragma unroll 4
    for (int c=0;c<64;c++){
        float uv = uls[lq][c];
        float2 d01 = *reinterpret_cast<const float2*>(&xwt[c][0]);
        t0 += d01.x*uv; t1 += d01.y*uv;
        float2 p0 = *reinterpret_cast<const float2*>(&xwt[c][rb]);
        float2 p1 = *reinterpret_cast<const float2*>(&xwt[c][rb+2]);
        float2 p2 = *reinterpret_cast<const float2*>(&xwt[c][rb+4]);
        float2 p3 = *reinterpret_cast<const float2*>(&xwt[c][rb+6]);
        acc[0]+=p0.x*uv; acc[1]+=p0.y*uv; acc[2]+=p1.x*uv; acc[3]+=p1.y*uv;
        acc[4]+=p2.x*uv; acc[5]+=p2.y*uv; acc[6]+=p3.x*uv; acc[7]+=p3.y*uv;
    }
    float* BC = (dc<2)? (Bp + l*16 + dc*8) : (Cp + l*16 + (dc-2)*8);
    *reinterpret_cast<float4*>(BC)   = make_float4(acc[0],acc[1],acc[2],acc[3]);
    *reinterpret_cast<float4*>(BC+4) = make_float4(acc[4],acc[5],acc[6],acc[7]);

    float dl16[16];
    #pragma unroll
    for (int dd=0; dd<16; dd++){
        int d = d0+dd;
        float tt = t0*dw[d*2] + t1*dw[d*2+1] + db[d];
        dl16[dd] = softplus_(tt);
    }
    #pragma unroll
    for (int q=0;q<4;q++)
        *reinterpret_cast<float4*>(dp + l*64 + d0 + q*4) =
            make_float4(dl16[q*4], dl16[q*4+1], dl16[q*4+2], dl16[q*4+3]);
}

// scan pass 1: per-chunk aggregates (prod of dA, end state with h_in = 0)
__global__ void k_scan1(const float* __restrict__ dlf, const float* __restrict__ Bf, const float* __restrict__ ufp,
                        const float* __restrict__ dlb, const float* __restrict__ Bb, const float* __restrict__ ubp,
                        const float* __restrict__ Af, const float* __restrict__ Ab,
                        float* __restrict__ chA, float* __restrict__ chB)
{
    int tid = threadIdx.x;                 // d*16+n
    int c = blockIdx.x, gd = blockIdx.y;
    const float* dl = gd? dlb:dlf; const float* Bv = gd? Bb:Bf; const float* u = gd? ubp:ufp;
    float A = -__expf((gd? Ab:Af)[tid]);
    int d = tid>>4, n = tid&15;
    float h=0.f, p=1.f;
    int base = c*LC;
    #pragma unroll 4
    for (int i=0;i<LC;i++){
        int l = base+i;
        float dv = dl[l*64+d];
        float da = __expf(dv*A);
        float bu = dv * Bv[l*16+n] * u[l*64+d];
        h = da*h + bu;
        p *= da;
    }
    int o = (gd*NC + c)*1024 + tid;
    chA[o]=p; chB[o]=h;
}

// scan of chunk aggregates -> incoming state per chunk
__global__ void k_scan_agg(const float* __restrict__ chA, const float* __restrict__ chB,
                           float* __restrict__ hst)
{
    int tid = threadIdx.x; int gd = blockIdx.x;
    float h=0.f;
    #pragma unroll 8
    for (int c=0;c<NC;c++){
        int o = (gd*NC + c)*1024 + tid;
        hst[o]=h;
        h = chA[o]*h + chB[o];
    }
}

// scan pass 2: replay with correct h_in, emit y (+ u*D); backward writes reversed
__global__ void k_scan2(const float* __restrict__ dlf, const float* __restrict__ Bf,
                        const float* __restrict__ Cf, const float* __restrict__ ufp,
                        const float* __restrict__ dlb, const float* __restrict__ Bb,
                        const float* __restrict__ Cb, const float* __restrict__ ubp,
                        const float* __restrict__ Af, const float* __restrict__ Ab,
                        const float* __restrict__ Dfp, const float* __restrict__ Dbp,
                        const float* __restrict__ hst,
                        float* __restrict__ yf, float* __restrict__ yb)
{
    int tid = threadIdx.x;
    int c = blockIdx.x, gd = blockIdx.y;
    const float* dl = gd? dlb:dlf; const float* Bv = gd? Bb:Bf;
    const float* Cv = gd? Cb:Cf;  const float* u  = gd? ubp:ufp;
    float A = -__expf((gd? Ab:Af)[tid]);
    int d = tid>>4, n = tid&15;
    float Dd = (gd? Dbp:Dfp)[d];
    float h = hst[(gd*NC + c)*1024 + tid];
    int base = c*LC;
    for (int i=0;i<LC;i++){
        int l = base+i;
        float dv = dl[l*64+d];
        float uu = u[l*64+d];
        float da = __expf(dv*A);
        h = da*h + dv * Bv[l*16+n] * uu;
        float t = h * Cv[l*16+n];
        t += __shfl_xor(t,1,16); t += __shfl_xor(t,2,16);
        t += __shfl_xor(t,4,16); t += __shfl_xor(t,8,16);
        if (n==0){
            float r = t + uu*Dd;
            if (gd) yb[(L-1-l)*64+d] = r;
            else    yf[l*64+d]       = r;
        }
    }
}

// silu(z)*(yf+yb) @ out_proj^T -> x_mamba [32][L], LDS-staged weights.
// grid (L/64), block 256.
__global__ __launch_bounds__(256,2)
void k_combine(const float* __restrict__ yf, const float* __restrict__ yb,
               const float* __restrict__ z, const float* __restrict__ opw,
               float* __restrict__ xm)
{
    __shared__ float yls[64][65];
    __shared__ float ot[64][36];      // ot[c][j] = opw[j*64+c], j<32
    int t  = threadIdx.x;
    int lq = t>>2, dc = t&3;
    int l  = blockIdx.x*64 + lq;
    int d0 = dc*16;

    #pragma unroll
    for (int k=0;k<8;k++){
        int idx = t + k*256;          // 2048 = 32x64
        int j = idx>>6, c = idx&63;
        ot[c][j] = opw[idx];
    }

    #pragma unroll
    for (int q=0;q<4;q++){
        float4 a = *reinterpret_cast<const float4*>(yf + l*64 + d0 + q*4);
        float4 bq= *reinterpret_cast<const float4*>(yb + l*64 + d0 + q*4);
        float4 zq= *reinterpret_cast<const float4*>(z  + l*64 + d0 + q*4);
        yls[lq][d0+q*4+0] = (a.x+bq.x)*(zq.x*sigm(zq.x));
        yls[lq][d0+q*4+1] = (a.y+bq.y)*(zq.y*sigm(zq.y));
        yls[lq][d0+q*4+2] = (a.z+bq.z)*(zq.z*sigm(zq.z));
        yls[lq][d0+q*4+3] = (a.w+bq.w)*(zq.w*sigm(zq.w));
    }
    __syncthreads();

    float acc[8];
    #pragma unroll
    for (int jj=0;jj<8;jj++) acc[jj]=0.f;
    #pragma unroll 4
    for (int c=0;c<64;c++){
        float uv = yls[lq][c];
        float4 w0 = *reinterpret_cast<const float4*>(&ot[c][dc*8]);
        float4 w1 = *reinterpret_cast<const float4*>(&ot[c][dc*8+4]);
        acc[0]+=w0.x*uv; acc[1]+=w0.y*uv; acc[2]+=w0.z*uv; acc[3]+=w0.w*uv;
        acc[4]+=w1.x*uv; acc[5]+=w1.y*uv; acc[6]+=w1.z*uv; acc[7]+=w1.w*uv;
    }
    #pragma unroll
    for (int jj=0;jj<8;jj++) xm[(dc*8+jj)*L+l] = acc[jj];
}

// ---------------- conv3d branch ----------------

// 1x1x1 conv (32->32) + per-channel {sum,sumsq} stats (used for cp1 and cp2)
__global__ void k_conv1x1(const float* __restrict__ in, const float* __restrict__ w,
                          const float* __restrict__ b, float* __restrict__ out,
                          float* __restrict__ st)
{
    int oc = blockIdx.x; int l0 = blockIdx.y*(L/8);
    float s=0.f, s2=0.f;
    for (int l=l0+threadIdx.x; l<l0+L/8; l+=256){
        float acc = b[oc];
        #pragma unroll
        for (int ic=0;ic<32;ic++) acc += w[oc*32+ic]*in[ic*L+l];
        out[oc*L+l]=acc; s+=acc; s2+=acc*acc;
    }
    block_accum2(s,s2, st+oc, st+32+oc);
}

// instance-norm (stats already summed) + leaky relu, in place
__global__ void k_norm(float* __restrict__ buf, const float* __restrict__ st)
{
    int oc = blockIdx.x; int l0 = blockIdx.y*(L/8);
    float mu  = st[oc]*(1.0f/(float)L);
    float var = st[32+oc]*(1.0f/(float)L) - mu*mu;
    float inv = rsqrtf(var + 1e-5f);
    for (int l=l0+threadIdx.x; l<l0+L/8; l+=256){
        float v = (buf[oc*L+l]-mu)*inv;
        buf[oc*L+l] = (v>=0.0f)? v : 0.1f*v;
    }
}

// instance-norm + lrelu for H1, writing both in-place (residual use) and a zero-padded copy
__global__ void k_norm_pad(float* __restrict__ buf, const float* __restrict__ st,
                           float* __restrict__ pad)
{
    int oc = blockIdx.x; int l0 = blockIdx.y*(L/8);
    float mu  = st[oc]*(1.0f/(float)L);
    float var = st[32+oc]*(1.0f/(float)L) - mu*mu;
    float inv = rsqrtf(var + 1e-5f);
    for (int l=l0+threadIdx.x; l<l0+L/8; l+=256){
        float v = (buf[oc*L+l]-mu)*inv;
        v = (v>=0.0f)? v : 0.1f*v;
        buf[oc*L+l] = v;
        int zx = l>>9, yy=(l>>4)&31, xx=l&15;
        pad[oc*PCH + (zx+2)*PSZ + (yy+2)*PSY + (xx+2)] = v;
    }
}

// the 4 ELK convs (3x3x3, 5x1x1, 1x5x1, 1x1x5), 32->16 each, on padded input.
// k_elk is LDS-ISSUE-BOUND (~37 ds_read_b32/ic/thread); the lever is tap REUSE:
// 4 ocs per thread amortize each tap 4x (16 E4 outputs per 37 taps).
// grid (64, 4) = 256 blocks (1/CU), block 256.
__global__ __launch_bounds__(256,2)
void k_elk(const float* __restrict__ hp,
           const float* __restrict__ w1, const float* __restrict__ b1,
           const float* __restrict__ w2, const float* __restrict__ b2,
           const float* __restrict__ w3, const float* __restrict__ b3,
           const float* __restrict__ w4, const float* __restrict__ b4,
           float* __restrict__ e)
{
    __shared__ float tile[2][TILE_N];  // 2 x 2400 floats, x-stride 24
    int t  = threadIdx.x;
    int b  = blockIdx.x;
    int z0 = b>>1, yh = (b&1)*16;
    int ty = t>>4, tx = t&15;
    int l  = z0*512 + (yh+ty)*16 + tx;
    int oc0 = blockIdx.y*4;            // 4 ocs per thread
    const float* src0 = hp + z0*PSZ + yh*PSY;
    int co = 2*TSZ + (ty+2)*TSX + (tx+2);   // center offset (z=2 plane)

    float a1[4], a2[4], a3[4], a4[4];
    #pragma unroll
    for (int o=0;o<4;o++){
        a1[o]=b1[oc0+o]; a2[o]=b2[oc0+o]; a3[o]=b3[oc0+o]; a4[o]=b4[oc0+o];
    }

    // stage first channel: iterate PADDED index space -> LDS writes are
    // consecutive addresses (conflict-free); pad columns (xx>=20) get zeros.
    #pragma unroll
    for (int k=0;k<10;k++){
        int idx = t + k*256;
        if (idx < TILE_N){
            int zz = idx/TSZ, rem = idx - zz*TSZ;
            int yy = rem/TSX, xx = rem - yy*TSX;
            tile[0][idx] = (xx<20) ? src0[zz*PSZ + yy*PSY + xx] : 0.0f;
        }
    }
    __syncthreads();

    for (int ic=0; ic<32; ic++){
        int cur = ic&1;
        // prefetch next channel into registers (T14: issue before compute)
        float r[10];
        if (ic<31){
            const float* srcn = src0 + (ic+1)*PCH;
            #pragma unroll
            for (int k=0;k<10;k++){
                int idx = t + k*256;
                float v = 0.0f;
                if (idx < TILE_N){
                    int zz = idx/TSZ, rem = idx - zz*TSZ;
                    int yy = rem/TSX, xx = rem - yy*TSX;
                    if (xx<20) v = srcn[zz*PSZ + yy*PSY + xx];
                }
                r[k] = v;
            }
        }
        const float* tl = tile[cur];
        // gather taps from LDS ONCE per ic (balanced 2-way banks -> free per m136)
        float v[27];
        #pragma unroll
        for (int dz=0;dz<3;dz++)
        #pragma unroll
        for (int dy=0;dy<3;dy++)
        #pragma unroll
        for (int dx=0;dx<3;dx++)
            v[(dz*3+dy)*3+dx] = tl[co + (dz-1)*TSZ + (dy-1)*TSX + (dx-1)];
        float z5[5], y5[5], x5[5];
        #pragma unroll
        for (int q=0;q<5;q++){
            z5[q] = tl[co + (q-2)*TSZ];
            y5[q] = tl[co + (q-2)*TSX];
            x5[q] = tl[co + (q-2)];
        }
        // 4 ocs reuse the same taps; weights wave-uniform -> s_load/K$
        #pragma unroll
        for (int o=0;o<4;o++){
            const float* wp1 = w1 + ((oc0+o)*32+ic)*27;
            float a = a1[o];
            #pragma unroll
            for (int q=0;q<27;q++) a += wp1[q]*v[q];
            a1[o]=a;
            const float* wp2 = w2 + ((oc0+o)*32+ic)*5;
            const float* wp3 = w3 + ((oc0+o)*32+ic)*5;
            const float* wp4 = w4 + ((oc0+o)*32+ic)*5;
            float s2a=a2[o], s3a=a3[o], s4a=a4[o];
            #pragma unroll
            for (int q=0;q<5;q++){
                s2a += wp2[q]*z5[q];
                s3a += wp3[q]*y5[q];
                s4a += wp4[q]*x5[q];
            }
            a2[o]=s2a; a3[o]=s3a; a4[o]=s4a;
        }
        if (ic<31){
            // write prefetched channel (consecutive LDS addresses, conflict-free)
            #pragma unroll
            for (int k=0;k<10;k++){
                int idx = t + k*256;
                if (idx < TILE_N) tile[cur^1][idx] = r[k];
            }
            __syncthreads();
        }
    }
    #pragma unroll
    for (int o=0;o<4;o++){
        e[(oc0+o)*L+l]      = a1[o];
        e[(16+oc0+o)*L+l]   = a2[o];
        e[(32+oc0+o)*L+l]   = a3[o];
        e[(48+oc0+o)*L+l]   = a4[o];
    }
}

// elk5 (1x1x1, 64->32) + residual + stats; grid (32,16) for occupancy
__global__ void k_elk5(const float* __restrict__ e, const float* __restrict__ hres,
                       const float* __restrict__ w, const float* __restrict__ b,
                       float* __restrict__ h2, float* __restrict__ st)
{
    int oc = blockIdx.x; int l0 = blockIdx.y*(L/16);
    float s=0.f, s2=0.f;
    for (int l=l0+threadIdx.x; l<l0+L/16; l+=256){
        float acc = b[oc];
        #pragma unroll
        for (int m=0;m<64;m++) acc += w[oc*64+m]*e[m*L+l];
        acc += hres[oc*L+l];
        h2[oc*L+l]=acc; s+=acc; s2+=acc*acc;
    }
    block_accum2(s,s2, st+oc, st+32+oc);
}

// ---------------- fusion ----------------

__global__ void k_pool(const float* __restrict__ h3, const float* __restrict__ xm,
                       float* __restrict__ pooled)
{
    int fc = blockIdx.x; int l0 = blockIdx.y*(L/8);
    const float* src = (fc&1) ? xm + (fc>>1)*L : h3 + (fc>>1)*L;
    float s=0.f;
    for (int l=l0+threadIdx.x; l<l0+L/8; l+=256) s += src[l];
    #pragma unroll
    for (int m=1;m<64;m<<=1) s += __shfl_xor(s,m,64);
    __shared__ float red[4];
    int lane = threadIdx.x&63, wid = threadIdx.x>>6;
    if (lane==0) red[wid]=s;
    __syncthreads();
    if (threadIdx.x==0) atomicAdd(pooled+fc, red[0]+red[1]+red[2]+red[3]);
}

__global__ void k_attn(const float* __restrict__ pooled, const float* __restrict__ aw,
                       float* __restrict__ attn)
{
    __shared__ float pl[64];
    int t = threadIdx.x;
    pl[t] = pooled[t]*(1.0f/(float)L);
    __syncthreads();
    float acc=0.f;
    #pragma unroll
    for (int c=0;c<64;c++) acc += aw[t*64+c]*pl[c];
    attn[t] = sigm(sigm(acc));
}

// final: conv2 gate + attn scale + 1x1 conv1, with w1/attn/c2w staged in LDS.
// grid (L/256, 4), block 256.
__global__ __launch_bounds__(256,2)
void k_final(const float* __restrict__ h3, const float* __restrict__ xm,
             const float* __restrict__ attn, const float* __restrict__ w1,
             const float* __restrict__ c2w, const float* __restrict__ c2b,
             float* __restrict__ out)
{
    __shared__ float w1s[64][20];   // w1s[fused c][o]; 20-float rows = 80B (16B-aligned)
    __shared__ float sA[64], sG[64];
    int t = threadIdx.x;
    int o0 = blockIdx.y*16;

    #pragma unroll
    for (int k=0;k<4;k++){
        int idx = t + k*256;        // 1024 = 16 o x 64 c
        int o = idx>>6, c = idx&63;
        w1s[c][o] = w1[(o0+o)*64 + c];
    }
    if (t < 64){ sA[t] = attn[t]; sG[t] = c2w[t]; }
    __syncthreads();

    int l = blockIdx.x*blockDim.x + t;
    float acc[16];
    #pragma unroll
    for (int o=0;o<16;o++) acc[o]=0.f;
    float a2 = c2b[0];
    #pragma unroll 4
    for (int i=0;i<32;i++){
        float hv = h3[i*L+l];
        float xv = xm[i*L+l];
        a2 += sG[i]*hv + sG[32+i]*xv;     // xcat order: [h3(0..31), xm(0..31)]
        float fh = hv*sA[2*i];            // fused (interleaved) channel 2i
        float fx = xv*sA[2*i+1];          //                        channel 2i+1
        float4 p0 = *reinterpret_cast<const float4*>(&w1s[2*i][0]);
        float4 p1 = *reinterpret_cast<const float4*>(&w1s[2*i][4]);
        float4 p2 = *reinterpret_cast<const float4*>(&w1s[2*i][8]);
        float4 p3 = *reinterpret_cast<const float4*>(&w1s[2*i][12]);
        float4 q0 = *reinterpret_cast<const float4*>(&w1s[2*i+1][0]);
        float4 q1 = *reinterpret_cast<const float4*>(&w1s[2*i+1][4]);
        float4 q2 = *reinterpret_cast<const float4*>(&w1s[2*i+1][8]);
        float4 q3 = *reinterpret_cast<const float4*>(&w1s[2*i+1][12]);
        acc[0] += p0.x*fh + q0.x*fx;  acc[1] += p0.y*fh + q0.y*fx;
        acc[2] += p0.z*fh + q0.z*fx;  acc[3] += p0.w*fh + q0.w*fx;
        acc[4] += p1.x*fh + q1.x*fx;  acc[5] += p1.y*fh + q1.y*fx;
        acc[6] += p1.z*fh + q1.z*fx;  acc[7] += p1.w*fh + q1.w*fx;
        acc[8] += p2.x*fh + q2.x*fx;  acc[9] += p2.y*fh + q2.y*fx;
        acc[10]+= p2.z*fh + q2.z*fx;  acc[11]+= p2.w*fh + q2.w*fx;
        acc[12]+= p3.x*fh + q3.x*fx;  acc[13]+= p3.y*fh + q3.y*fx;
        acc[14]+= p3.z*fh + q3.z*fx;  acc[15]+= p3.w*fh + q3.w*fx;
    }
    float at2 = sigm(a2);
    #pragma unroll
    for (int o=0;o<16;o++) out[(o0+o)*L+l] = acc[o]*at2;
}

// ---------------- launch ----------------

extern "C" void kernel_launch(void* const* d_in, const int* in_sizes, int n_in,
                              void* d_out, int out_size, void* d_ws, size_t ws_size,
                              hipStream_t stream)
{
    const float* x         = (const float*)d_in[0];
    const float* ln_g      = (const float*)d_in[1];
    const float* ln_b      = (const float*)d_in[2];
    const float* in_proj_w = (const float*)d_in[3];
    const float* conv1d_w  = (const float*)d_in[4];
    const float* conv1d_b  = (const float*)d_in[5];
    const float* x_proj_w  = (const float*)d_in[6];
    const float* dt_proj_w = (const float*)d_in[7];
    const float* dt_proj_b = (const float*)d_in[8];
    const float* A_log     = (const float*)d_in[9];
    const float* D_f       = (const float*)d_in[10];
    const float* conv1db_w = (const float*)d_in[11];
    const float* conv1db_b = (const float*)d_in[12];
    const float* x_projb_w = (const float*)d_in[13];
    const float* dt_projb_w= (const float*)d_in[14];
    const float* dt_projb_b= (const float*)d_in[15];
    const float* Ab_log    = (const float*)d_in[16];
    const float* D_b       = (const float*)d_in[17];
    const float* out_proj_w= (const float*)d_in[18];
    const float* cp1_w     = (const float*)d_in[19];
    const float* cp1_b     = (const float*)d_in[20];
    const float* elk1_w    = (const float*)d_in[21];
    const float* elk1_b    = (const float*)d_in[22];
    const float* elk2_w    = (const float*)d_in[23];
    const float* elk2_b    = (const float*)d_in[24];
    const float* elk3_w    = (const float*)d_in[25];
    const float* elk3_b    = (const float*)d_in[26];
    const float* elk4_w    = (const float*)d_in[27];
    const float* elk4_b    = (const float*)d_in[28];
    const float* elk5_w    = (const float*)d_in[29];
    const float* elk5_b    = (const float*)d_in[30];
    const float* cp2_w     = (const float*)d_in[31];
    const float* cp2_b     = (const float*)d_in[32];
    const float* atten_w   = (const float*)d_in[33];
    const float* conv1_w   = (const float*)d_in[34];
    const float* conv2_w   = (const float*)d_in[35];
    const float* conv2_b   = (const float*)d_in[36];

    float* ws = (float*)d_ws;
    // workspace layout (floats)
    float* XI  = ws + 0;          // [64][L] (dead after k_conv_proj; reused as H1P)
    float* Z   = ws + 1048576;    // [L][64]
    float* UF  = ws + 2097152;    // [L][64]
    float* UB  = ws + 3145728;
    float* DLF = ws + 4194304;    // [L][64]
    float* DLB = ws + 5242880;
    float* BF  = ws + 6291456;    // [L][16]
    float* CF  = ws + 6553600;
    float* BB  = ws + 6815744;
    float* CB  = ws + 7077888;
    float* CHA = ws + 7340032;    // [2][NC][1024]
    float* CHB = ws + 7864320;
    float* HST = ws + 8388608;
    float* YF  = ws + 8912896;    // [L][64]
    float* YB  = ws + 9961472;    // [L][64]
    float* XM  = ws + 11010048;   // [32][L]
    float* H1  = ws + 11534336;   // [32][L]
    float* E4  = ws + 12058624;   // [64][L]
    float* H2  = ws + 13107200;
    float* H3  = ws + 13631488;
    float* ST  = ws + 14155776;   // stats1[64] stats2[64] stats3[64] pooled[64] attn[64]
    float* H1P = XI;              // padded H1: 32*PCH = 829440 floats < 1048576 (XI region)

    hipMemsetAsync(ST, 0, 256*sizeof(float), stream);

    // mamba branch (pre-scan) — uses XI
    k_ln_proj<<<dim3(L/64,4), 256, 0, stream>>>(x, ln_g, ln_b, in_proj_w, XI, Z);
    k_conv_proj<<<dim3(L/64,2), 256, 0, stream>>>(XI,
        conv1d_w, conv1d_b, x_proj_w, dt_proj_w, dt_proj_b,
        conv1db_w, conv1db_b, x_projb_w, dt_projb_w, dt_projb_b,
        UF, DLF, BF, CF, UB, DLB, BB, CB);
    k_scan1<<<dim3(NC,2), 1024, 0, stream>>>(DLF, BF, UF, DLB, BB, UB, A_log, Ab_log, CHA, CHB);
    k_scan_agg<<<2, 1024, 0, stream>>>(CHA, CHB, HST);
    k_scan2<<<dim3(NC,2), 1024, 0, stream>>>(DLF, BF, CF, UF, DLB, BB, CB, UB,
                                             A_log, Ab_log, D_f, D_b, HST, YF, YB);
    k_combine<<<dim3(L/64), 256, 0, stream>>>(YF, YB, Z, out_proj_w, XM);

    // conv3d branch — XI is now dead, reuse as padded H1
    k_conv1x1<<<dim3(32,8), 256, 0, stream>>>(x, cp1_w, cp1_b, H1, ST);
    hipMemsetAsync(H1P, 0, 32*PCH*sizeof(float), stream);
    k_norm_pad<<<dim3(32,8), 256, 0, stream>>>(H1, ST, H1P);
    k_elk<<<dim3(L/256,4), 256, 0, stream>>>(H1P, elk1_w, elk1_b, elk2_w, elk2_b,
                                             elk3_w, elk3_b, elk4_w, elk4_b, E4);
    k_elk5<<<dim3(32,16), 256, 0, stream>>>(E4, H1, elk5_w, elk5_b, H2, ST+64);
    k_norm<<<dim3(32,8), 256, 0, stream>>>(H2, ST+64);
    k_conv1x1<<<dim3(32,8), 256, 0, stream>>>(H2, cp2_w, cp2_b, H3, ST+128);
    k_norm<<<dim3(32,8), 256, 0, stream>>>(H3, ST+128);

    // fusion
    k_pool<<<dim3(64,8), 256, 0, stream>>>(H3, XM, ST+192);
    k_attn<<<1, 64, 0, stream>>>(ST+192, atten_w, ST+256);
    k_final<<<dim3(L/256,4), 256, 0, stream>>>(H3, XM, ST+256, conv1_w, conv2_w, conv2_b,
                                               (float*)d_out);
}

// Round 16
// 368.454 us; speedup vs baseline: 1.1825x; 1.1825x over previous
//
#include <hip/hip_runtime.h>
#include <math.h>

// Problem dims (fixed by setup_inputs)
constexpr int L  = 16384;   // 32*32*16 spatial (z=32, y=32, x=16)
constexpr int LC = 64;      // scan chunk length
constexpr int NC = 256;     // L / LC chunks

// padded volume for ELK convs: halo 2 on every side
constexpr int PX = 20, PY = 36, PZ = 36;
constexpr int PSY = PX;            // y stride
constexpr int PSZ = PY*PX;         // z stride = 720
constexpr int PCH = PZ*PSZ;        // channel stride = 25920

__device__ __forceinline__ float sigm(float x){ return 1.0f/(1.0f+__expf(-x)); }
__device__ __forceinline__ float softplus_(float x){ return (x>20.0f)? x : log1pf(__expf(x)); }

// block-wide {sum, sumsq} accumulation into global via atomics (256-thread blocks)
__device__ __forceinline__ void block_accum2(float s, float s2, float* g0, float* g1){
    #pragma unroll
    for (int m=1;m<64;m<<=1){ s += __shfl_xor(s,m,64); s2 += __shfl_xor(s2,m,64); }
    __shared__ float red[16];
    int lane = threadIdx.x & 63, wid = threadIdx.x >> 6;
    if (lane==0){ red[wid]=s; red[8+wid]=s2; }
    __syncthreads();
    if (threadIdx.x==0){
        int nw = blockDim.x >> 6;
        float a=0.f,b=0.f;
        for (int i=0;i<nw;i++){ a+=red[i]; b+=red[8+i]; }
        atomicAdd(g0,a); atomicAdd(g1,b);
    }
}

// ---------------- Mamba branch ----------------

// LayerNorm over 32 channels + in_proj (32->128), LDS-staged weights.
// grid (L/64, 4), block 256.
__global__ __launch_bounds__(256,2)
void k_ln_proj(const float* __restrict__ x, const float* __restrict__ g,
               const float* __restrict__ b, const float* __restrict__ w,
               float* __restrict__ xi, float* __restrict__ z)
{
    __shared__ float xn[64][33];      // [l][c]
    __shared__ float wt[32][36];      // wt[c][j] = w[(j0b+j)*32+c]
    int t  = threadIdx.x;
    int lq = t>>2, dc = t&3;
    int l  = blockIdx.x*64 + lq;
    int c0 = dc*8;
    int j0b = blockIdx.y*32;

    // stage weights transposed (coalesced reads)
    #pragma unroll
    for (int k=0;k<4;k++){
        int idx = t + k*256;          // 1024 = 32x32
        int j = idx>>5, c = idx&31;
        wt[c][j] = w[(j0b+j)*32+c];
    }

    float xv[8]; float s=0.f, s2=0.f;
    #pragma unroll
    for (int cc=0;cc<8;cc++){
        float v = x[(32+c0+cc)*L + l];
        xv[cc]=v; s+=v; s2+=v*v;
    }
    // quartet butterfly over 2 scalars
    #pragma unroll
    for (int m=1;m<4;m<<=1){ s += __shfl_xor(s,m,64); s2 += __shfl_xor(s2,m,64); }
    float mu  = s*(1.0f/32.0f);
    float var = s2*(1.0f/32.0f) - mu*mu;
    float inv = rsqrtf(var + 1e-5f);
    #pragma unroll
    for (int cc=0;cc<8;cc++)
        xn[lq][c0+cc] = (xv[cc]-mu)*inv*g[c0+cc] + b[c0+cc];
    __syncthreads();

    float acc[8];
    #pragma unroll
    for (int jj=0;jj<8;jj++) acc[jj]=0.f;
    #pragma unroll 4
    for (int c=0;c<32;c++){
        float uv = xn[lq][c];
        float4 w0 = *reinterpret_cast<const float4*>(&wt[c][dc*8]);
        float4 w1 = *reinterpret_cast<const float4*>(&wt[c][dc*8+4]);
        acc[0]+=w0.x*uv; acc[1]+=w0.y*uv; acc[2]+=w0.z*uv; acc[3]+=w0.w*uv;
        acc[4]+=w1.x*uv; acc[5]+=w1.y*uv; acc[6]+=w1.z*uv; acc[7]+=w1.w*uv;
    }
    int j0 = j0b + dc*8;
    if (j0 < 64){
        #pragma unroll
        for (int jj=0;jj<8;jj++) xi[(j0+jj)*L+l] = acc[jj];
    } else {
        #pragma unroll
        for (int q=0;q<2;q++)
            *reinterpret_cast<float4*>(z + l*64 + (j0-64) + q*4) =
                make_float4(acc[q*4], acc[q*4+1], acc[q*4+2], acc[q*4+3]);
    }
}

// depthwise causal conv1d + SiLU + x_proj + dt_proj(softplus), LDS-staged weights.
// grid (L/64, 2), block 256.
__global__ __launch_bounds__(256,2)
void k_conv_proj(const float* __restrict__ xi,
    const float* __restrict__ cwf, const float* __restrict__ cbf,
    const float* __restrict__ xwf, const float* __restrict__ dwf, const float* __restrict__ dbf,
    const float* __restrict__ cwb, const float* __restrict__ cbb,
    const float* __restrict__ xwb, const float* __restrict__ dwb, const float* __restrict__ dbb,
    float* __restrict__ uf, float* __restrict__ dlf, float* __restrict__ Bfp, float* __restrict__ Cfp,
    float* __restrict__ ub, float* __restrict__ dlb, float* __restrict__ Bbp, float* __restrict__ Cbp)
{
    __shared__ float uls[64][65];     // [l][d]
    __shared__ float xwt[64][36];     // xwt[c][r] = xw[r*64+c], r<34 (dt0,dt1,B0-15,C0-15)
    int t  = threadIdx.x;
    int lq = t>>2, dc = t&3;
    int l  = blockIdx.x*64 + lq;
    int d0 = dc*16;
    int gd = blockIdx.y;
    const float* cw = gd? cwb:cwf; const float* cb = gd? cbb:cbf;
    const float* xw = gd? xwb:xwf; const float* dw = gd? dwb:dwf; const float* db = gd? dbb:dbf;
    float* up = gd? ub:uf; float* dp = gd? dlb:dlf;
    float* Bp = gd? Bbp:Bfp; float* Cp = gd? Cbp:Cfp;

    // stage x_proj weights transposed
    #pragma unroll
    for (int k=0;k<9;k++){
        int idx = t + k*256;          // 2176 = 34x64
        if (idx < 34*64){
            int r = idx>>6, c = idx&63;
            xwt[c][r] = xw[idx];
        }
    }

    // phase 1: conv + SiLU for 16 channels
    float u16[16];
    #pragma unroll
    for (int dd=0; dd<16; dd++){
        int d = d0+dd;
        float s = cb[d];
        #pragma unroll
        for (int k=0;k<4;k++){
            int j = l-3+k;                       // position in (possibly reversed) sequence
            float v = 0.0f;
            if (j>=0) v = xi[d*L + (gd ? (L-1-j) : j)];
            s += cw[d*4+k]*v;
        }
        float u = s*sigm(s);                     // SiLU
        u16[dd] = u;
        uls[lq][d] = u;
    }
    #pragma unroll
    for (int q=0;q<4;q++)
        *reinterpret_cast<float4*>(up + l*64 + d0 + q*4) =
            make_float4(u16[q*4], u16[q*4+1], u16[q*4+2], u16[q*4+3]);
    __syncthreads();

    // phase 2: 8 B/C rows per lane + dt (all lanes), from LDS
    float acc[8]; float t0=0.f, t1=0.f;
    #pragma unroll
    for (int jj=0;jj<8;jj++) acc[jj]=0.f;
    int rb = 2 + dc*8;
    #pragma unroll 4
    for (int c=0;c<64;c++){
        float uv = uls[lq][c];
        float2 d01 = *reinterpret_cast<const float2*>(&xwt[c][0]);
        t0 += d01.x*uv; t1 += d01.y*uv;
        float2 p0 = *reinterpret_cast<const float2*>(&xwt[c][rb]);
        float2 p1 = *reinterpret_cast<const float2*>(&xwt[c][rb+2]);
        float2 p2 = *reinterpret_cast<const float2*>(&xwt[c][rb+4]);
        float2 p3 = *reinterpret_cast<const float2*>(&xwt[c][rb+6]);
        acc[0]+=p0.x*uv; acc[1]+=p0.y*uv; acc[2]+=p1.x*uv; acc[3]+=p1.y*uv;
        acc[4]+=p2.x*uv; acc[5]+=p2.y*uv; acc[6]+=p3.x*uv; acc[7]+=p3.y*uv;
    }
    float* BC = (dc<2)? (Bp + l*16 + dc*8) : (Cp + l*16 + (dc-2)*8);
    *reinterpret_cast<float4*>(BC)   = make_float4(acc[0],acc[1],acc[2],acc[3]);
    *reinterpret_cast<float4*>(BC+4) = make_float4(acc[4],acc[5],acc[6],acc[7]);

    float dl16[16];
    #pragma unroll
    for (int dd=0; dd<16; dd++){
        int d = d0+dd;
        float tt = t0*dw[d*2] + t1*dw[d*2+1] + db[d];
        dl16[dd] = softplus_(tt);
    }
    #pragma unroll
    for (int q=0;q<4;q++)
        *reinterpret_cast<float4*>(dp + l*64 + d0 + q*4) =
            make_float4(dl16[q*4], dl16[q*4+1], dl16[q*4+2], dl16[q*4+3]);
}

// scan pass 1: per-chunk aggregates (prod of dA, end state with h_in = 0)
__global__ void k_scan1(const float* __restrict__ dlf, const float* __restrict__ Bf, const float* __restrict__ ufp,
                        const float* __restrict__ dlb, const float* __restrict__ Bb, const float* __restrict__ ubp,
                        const float* __restrict__ Af, const float* __restrict__ Ab,
                        float* __restrict__ chA, float* __restrict__ chB)
{
    int tid = threadIdx.x;                 // d*16+n
    int c = blockIdx.x, gd = blockIdx.y;
    const float* dl = gd? dlb:dlf; const float* Bv = gd? Bb:Bf; const float* u = gd? ubp:ufp;
    float A = -__expf((gd? Ab:Af)[tid]);
    int d = tid>>4, n = tid&15;
    float h=0.f, p=1.f;
    int base = c*LC;
    #pragma unroll 4
    for (int i=0;i<LC;i++){
        int l = base+i;
        float dv = dl[l*64+d];
        float da = __expf(dv*A);
        float bu = dv * Bv[l*16+n] * u[l*64+d];
        h = da*h + bu;
        p *= da;
    }
    int o = (gd*NC + c)*1024 + tid;
    chA[o]=p; chB[o]=h;
}

// scan of chunk aggregates -> incoming state per chunk
__global__ void k_scan_agg(const float* __restrict__ chA, const float* __restrict__ chB,
                           float* __restrict__ hst)
{
    int tid = threadIdx.x; int gd = blockIdx.x;
    float h=0.f;
    #pragma unroll 8
    for (int c=0;c<NC;c++){
        int o = (gd*NC + c)*1024 + tid;
        hst[o]=h;
        h = chA[o]*h + chB[o];
    }
}

// scan pass 2: replay with correct h_in, emit y (+ u*D); backward writes reversed
__global__ void k_scan2(const float* __restrict__ dlf, const float* __restrict__ Bf,
                        const float* __restrict__ Cf, const float* __restrict__ ufp,
                        const float* __restrict__ dlb, const float* __restrict__ Bb,
                        const float* __restrict__ Cb, const float* __restrict__ ubp,
                        const float* __restrict__ Af, const float* __restrict__ Ab,
                        const float* __restrict__ Dfp, const float* __restrict__ Dbp,
                        const float* __restrict__ hst,
                        float* __restrict__ yf, float* __restrict__ yb)
{
    int tid = threadIdx.x;
    int c = blockIdx.x, gd = blockIdx.y;
    const float* dl = gd? dlb:dlf; const float* Bv = gd? Bb:Bf;
    const float* Cv = gd? Cb:Cf;  const float* u  = gd? ubp:ufp;
    float A = -__expf((gd? Ab:Af)[tid]);
    int d = tid>>4, n = tid&15;
    float Dd = (gd? Dbp:Dfp)[d];
    float h = hst[(gd*NC + c)*1024 + tid];
    int base = c*LC;
    for (int i=0;i<LC;i++){
        int l = base+i;
        float dv = dl[l*64+d];
        float uu = u[l*64+d];
        float da = __expf(dv*A);
        h = da*h + dv * Bv[l*16+n] * uu;
        float t = h * Cv[l*16+n];
        t += __shfl_xor(t,1,16); t += __shfl_xor(t,2,16);
        t += __shfl_xor(t,4,16); t += __shfl_xor(t,8,16);
        if (n==0){
            float r = t + uu*Dd;
            if (gd) yb[(L-1-l)*64+d] = r;
            else    yf[l*64+d]       = r;
        }
    }
}

// silu(z)*(yf+yb) @ out_proj^T -> x_mamba [32][L], LDS-staged weights.
// grid (L/64), block 256.
__global__ __launch_bounds__(256,2)
void k_combine(const float* __restrict__ yf, const float* __restrict__ yb,
               const float* __restrict__ z, const float* __restrict__ opw,
               float* __restrict__ xm)
{
    __shared__ float yls[64][65];
    __shared__ float ot[64][36];      // ot[c][j] = opw[j*64+c], j<32
    int t  = threadIdx.x;
    int lq = t>>2, dc = t&3;
    int l  = blockIdx.x*64 + lq;
    int d0 = dc*16;

    #pragma unroll
    for (int k=0;k<8;k++){
        int idx = t + k*256;          // 2048 = 32x64
        int j = idx>>6, c = idx&63;
        ot[c][j] = opw[idx];
    }

    #pragma unroll
    for (int q=0;q<4;q++){
        float4 a = *reinterpret_cast<const float4*>(yf + l*64 + d0 + q*4);
        float4 bq= *reinterpret_cast<const float4*>(yb + l*64 + d0 + q*4);
        float4 zq= *reinterpret_cast<const float4*>(z  + l*64 + d0 + q*4);
        yls[lq][d0+q*4+0] = (a.x+bq.x)*(zq.x*sigm(zq.x));
        yls[lq][d0+q*4+1] = (a.y+bq.y)*(zq.y*sigm(zq.y));
        yls[lq][d0+q*4+2] = (a.z+bq.z)*(zq.z*sigm(zq.z));
        yls[lq][d0+q*4+3] = (a.w+bq.w)*(zq.w*sigm(zq.w));
    }
    __syncthreads();

    float acc[8];
    #pragma unroll
    for (int jj=0;jj<8;jj++) acc[jj]=0.f;
    #pragma unroll 4
    for (int c=0;c<64;c++){
        float uv = yls[lq][c];
        float4 w0 = *reinterpret_cast<const float4*>(&ot[c][dc*8]);
        float4 w1 = *reinterpret_cast<const float4*>(&ot[c][dc*8+4]);
        acc[0]+=w0.x*uv; acc[1]+=w0.y*uv; acc[2]+=w0.z*uv; acc[3]+=w0.w*uv;
        acc[4]+=w1.x*uv; acc[5]+=w1.y*uv; acc[6]+=w1.z*uv; acc[7]+=w1.w*uv;
    }
    #pragma unroll
    for (int jj=0;jj<8;jj++) xm[(dc*8+jj)*L+l] = acc[jj];
}

// ---------------- conv3d branch ----------------

// 1x1x1 conv (32->32) + per-channel {sum,sumsq} stats (used for cp1 and cp2)
__global__ void k_conv1x1(const float* __restrict__ in, const float* __restrict__ w,
                          const float* __restrict__ b, float* __restrict__ out,
                          float* __restrict__ st)
{
    int oc = blockIdx.x; int l0 = blockIdx.y*(L/8);
    float s=0.f, s2=0.f;
    for (int l=l0+threadIdx.x; l<l0+L/8; l+=256){
        float acc = b[oc];
        #pragma unroll
        for (int ic=0;ic<32;ic++) acc += w[oc*32+ic]*in[ic*L+l];
        out[oc*L+l]=acc; s+=acc; s2+=acc*acc;
    }
    block_accum2(s,s2, st+oc, st+32+oc);
}

// instance-norm (stats already summed) + leaky relu, in place
__global__ void k_norm(float* __restrict__ buf, const float* __restrict__ st)
{
    int oc = blockIdx.x; int l0 = blockIdx.y*(L/8);
    float mu  = st[oc]*(1.0f/(float)L);
    float var = st[32+oc]*(1.0f/(float)L) - mu*mu;
    float inv = rsqrtf(var + 1e-5f);
    for (int l=l0+threadIdx.x; l<l0+L/8; l+=256){
        float v = (buf[oc*L+l]-mu)*inv;
        buf[oc*L+l] = (v>=0.0f)? v : 0.1f*v;
    }
}

// instance-norm + lrelu for H1, writing both in-place (residual use) and a zero-padded copy
__global__ void k_norm_pad(float* __restrict__ buf, const float* __restrict__ st,
                           float* __restrict__ pad)
{
    int oc = blockIdx.x; int l0 = blockIdx.y*(L/8);
    float mu  = st[oc]*(1.0f/(float)L);
    float var = st[32+oc]*(1.0f/(float)L) - mu*mu;
    float inv = rsqrtf(var + 1e-5f);
    for (int l=l0+threadIdx.x; l<l0+L/8; l+=256){
        float v = (buf[oc*L+l]-mu)*inv;
        v = (v>=0.0f)? v : 0.1f*v;
        buf[oc*L+l] = v;
        int zx = l>>9, yy=(l>>4)&31, xx=l&15;
        pad[oc*PCH + (zx+2)*PSZ + (yy+2)*PSY + (xx+2)] = v;
    }
}

// the 4 ELK convs (3x3x3, 5x1x1, 1x5x1, 1x1x5), 32->16 each, on padded input.
// Best-measured variant (round 9, 43.0 µs): LDS-tiled input (5x20x20 halo,
// double-buffered), wave-uniform global weight loads (s_load/K$), 2 oc/thread.
// k_elk is at a measured plateau ~43 µs across structures — do not re-tune.
// grid (64, 8), block 256.
__global__ __launch_bounds__(256,2)
void k_elk(const float* __restrict__ hp,
           const float* __restrict__ w1, const float* __restrict__ b1,
           const float* __restrict__ w2, const float* __restrict__ b2,
           const float* __restrict__ w3, const float* __restrict__ b3,
           const float* __restrict__ w4, const float* __restrict__ b4,
           float* __restrict__ e)
{
    __shared__ float tile[2][2000];    // [5 z][20 y][20 x] flat, double-buffered
    int t  = threadIdx.x;
    int b  = blockIdx.x;
    int z0 = b>>1, yh = (b&1)*16;
    int ty = t>>4, tx = t&15;
    int l  = z0*512 + (yh+ty)*16 + tx;
    int oc0 = blockIdx.y*2;

    const float* src0 = hp + z0*PSZ + yh*PSY;
    int co = 800 + (ty+2)*20 + (tx+2);      // center offset: z=2 plane

    float a1[2],a2[2],a3[2],a4[2];
    #pragma unroll
    for (int o=0;o<2;o++){ a1[o]=b1[oc0+o]; a2[o]=b2[oc0+o]; a3[o]=b3[oc0+o]; a4[o]=b4[oc0+o]; }

    // stage ic=0 (each z-slice chunk of 400 floats is contiguous in padded layout)
    #pragma unroll
    for (int k=0;k<8;k++){
        int idx = t + k*256;
        if (idx < 2000){
            int zz = idx/400;
            tile[0][idx] = src0[zz*PSZ + (idx - zz*400)];
        }
    }
    __syncthreads();

    for (int ic=0; ic<32; ic++){
        int cur = ic&1;
        // prefetch next channel into registers (T14: issue before compute)
        float r[8];
        if (ic<31){
            const float* srcn = src0 + (ic+1)*PCH;
            #pragma unroll
            for (int k=0;k<8;k++){
                int idx = t + k*256;
                int zz = idx/400;
                r[k] = (idx<2000) ? srcn[zz*PSZ + (idx - zz*400)] : 0.0f;
            }
        }
        const float* tl = tile[cur];
        // gather taps from LDS
        float v[27];
        #pragma unroll
        for (int dz=0;dz<3;dz++)
        #pragma unroll
        for (int dy=0;dy<3;dy++)
        #pragma unroll
        for (int dx=0;dx<3;dx++)
            v[(dz*3+dy)*3+dx] = tl[co + (dz-1)*400 + (dy-1)*20 + (dx-1)];
        float z5[5], y5[5], x5[5];
        #pragma unroll
        for (int q=0;q<5;q++){
            z5[q] = tl[co + (q-2)*400];
            y5[q] = tl[co + (q-2)*20];
            x5[q] = tl[co + (q-2)];
        }
        #pragma unroll
        for (int o=0;o<2;o++){
            const float* wp1 = w1 + ((oc0+o)*32+ic)*27;   // wave-uniform -> s_load
            float a = a1[o];
            #pragma unroll
            for (int q=0;q<27;q++) a += wp1[q]*v[q];
            a1[o]=a;
            const float* wp2 = w2 + ((oc0+o)*32+ic)*5;
            const float* wp3 = w3 + ((oc0+o)*32+ic)*5;
            const float* wp4 = w4 + ((oc0+o)*32+ic)*5;
            float s2a=a2[o], s3a=a3[o], s4a=a4[o];
            #pragma unroll
            for (int q=0;q<5;q++){
                s2a += wp2[q]*z5[q];
                s3a += wp3[q]*y5[q];
                s4a += wp4[q]*x5[q];
            }
            a2[o]=s2a; a3[o]=s3a; a4[o]=s4a;
        }
        if (ic<31){
            // write prefetched channel into the other buffer; one barrier per ic
            #pragma unroll
            for (int k=0;k<8;k++){
                int idx = t + k*256;
                if (idx < 2000) tile[cur^1][idx] = r[k];
            }
            __syncthreads();
        }
    }
    #pragma unroll
    for (int o=0;o<2;o++){
        e[(oc0+o)*L+l]      = a1[o];
        e[(16+oc0+o)*L+l]   = a2[o];
        e[(32+oc0+o)*L+l]   = a3[o];
        e[(48+oc0+o)*L+l]   = a4[o];
    }
}

// elk5 (1x1x1, 64->32) + residual + stats; grid (32,16) for occupancy
__global__ void k_elk5(const float* __restrict__ e, const float* __restrict__ hres,
                       const float* __restrict__ w, const float* __restrict__ b,
                       float* __restrict__ h2, float* __restrict__ st)
{
    int oc = blockIdx.x; int l0 = blockIdx.y*(L/16);
    float s=0.f, s2=0.f;
    for (int l=l0+threadIdx.x; l<l0+L/16; l+=256){
        float acc = b[oc];
        #pragma unroll
        for (int m=0;m<64;m++) acc += w[oc*64+m]*e[m*L+l];
        acc += hres[oc*L+l];
        h2[oc*L+l]=acc; s+=acc; s2+=acc*acc;
    }
    block_accum2(s,s2, st+oc, st+32+oc);
}

// ---------------- fusion ----------------

__global__ void k_pool(const float* __restrict__ h3, const float* __restrict__ xm,
                       float* __restrict__ pooled)
{
    int fc = blockIdx.x; int l0 = blockIdx.y*(L/8);
    const float* src = (fc&1) ? xm + (fc>>1)*L : h3 + (fc>>1)*L;
    float s=0.f;
    for (int l=l0+threadIdx.x; l<l0+L/8; l+=256) s += src[l];
    #pragma unroll
    for (int m=1;m<64;m<<=1) s += __shfl_xor(s,m,64);
    __shared__ float red[4];
    int lane = threadIdx.x&63, wid = threadIdx.x>>6;
    if (lane==0) red[wid]=s;
    __syncthreads();
    if (threadIdx.x==0) atomicAdd(pooled+fc, red[0]+red[1]+red[2]+red[3]);
}

__global__ void k_attn(const float* __restrict__ pooled, const float* __restrict__ aw,
                       float* __restrict__ attn)
{
    __shared__ float pl[64];
    int t = threadIdx.x;
    pl[t] = pooled[t]*(1.0f/(float)L);
    __syncthreads();
    float acc=0.f;
    #pragma unroll
    for (int c=0;c<64;c++) acc += aw[t*64+c]*pl[c];
    attn[t] = sigm(sigm(acc));
}

// final: conv2 gate + attn scale + 1x1 conv1, with w1/attn/c2w staged in LDS.
// grid (L/256, 4), block 256.
__global__ __launch_bounds__(256,2)
void k_final(const float* __restrict__ h3, const float* __restrict__ xm,
             const float* __restrict__ attn, const float* __restrict__ w1,
             const float* __restrict__ c2w, const float* __restrict__ c2b,
             float* __restrict__ out)
{
    __shared__ float w1s[64][20];   // w1s[fused c][o]; 20-float rows = 80B (16B-aligned)
    __shared__ float sA[64], sG[64];
    int t = threadIdx.x;
    int o0 = blockIdx.y*16;

    #pragma unroll
    for (int k=0;k<4;k++){
        int idx = t + k*256;        // 1024 = 16 o x 64 c
        int o = idx>>6, c = idx&63;
        w1s[c][o] = w1[(o0+o)*64 + c];
    }
    if (t < 64){ sA[t] = attn[t]; sG[t] = c2w[t]; }
    __syncthreads();

    int l = blockIdx.x*blockDim.x + t;
    float acc[16];
    #pragma unroll
    for (int o=0;o<16;o++) acc[o]=0.f;
    float a2 = c2b[0];
    #pragma unroll 4
    for (int i=0;i<32;i++){
        float hv = h3[i*L+l];
        float xv = xm[i*L+l];
        a2 += sG[i]*hv + sG[32+i]*xv;     // xcat order: [h3(0..31), xm(0..31)]
        float fh = hv*sA[2*i];            // fused (interleaved) channel 2i
        float fx = xv*sA[2*i+1];          //                        channel 2i+1
        float4 p0 = *reinterpret_cast<const float4*>(&w1s[2*i][0]);
        float4 p1 = *reinterpret_cast<const float4*>(&w1s[2*i][4]);
        float4 p2 = *reinterpret_cast<const float4*>(&w1s[2*i][8]);
        float4 p3 = *reinterpret_cast<const float4*>(&w1s[2*i][12]);
        float4 q0 = *reinterpret_cast<const float4*>(&w1s[2*i+1][0]);
        float4 q1 = *reinterpret_cast<const float4*>(&w1s[2*i+1][4]);
        float4 q2 = *reinterpret_cast<const float4*>(&w1s[2*i+1][8]);
        float4 q3 = *reinterpret_cast<const float4*>(&w1s[2*i+1][12]);
        acc[0] += p0.x*fh + q0.x*fx;  acc[1] += p0.y*fh + q0.y*fx;
        acc[2] += p0.z*fh + q0.z*fx;  acc[3] += p0.w*fh + q0.w*fx;
        acc[4] += p1.x*fh + q1.x*fx;  acc[5] += p1.y*fh + q1.y*fx;
        acc[6] += p1.z*fh + q1.z*fx;  acc[7] += p1.w*fh + q1.w*fx;
        acc[8] += p2.x*fh + q2.x*fx;  acc[9] += p2.y*fh + q2.y*fx;
        acc[10]+= p2.z*fh + q2.z*fx;  acc[11]+= p2.w*fh + q2.w*fx;
        acc[12]+= p3.x*fh + q3.x*fx;  acc[13]+= p3.y*fh + q3.y*fx;
        acc[14]+= p3.z*fh + q3.z*fx;  acc[15]+= p3.w*fh + q3.w*fx;
    }
    float at2 = sigm(a2);
    #pragma unroll
    for (int o=0;o<16;o++) out[(o0+o)*L+l] = acc[o]*at2;
}

// ---------------- launch ----------------

extern "C" void kernel_launch(void* const* d_in, const int* in_sizes, int n_in,
                              void* d_out, int out_size, void* d_ws, size_t ws_size,
                              hipStream_t stream)
{
    const float* x         = (const float*)d_in[0];
    const float* ln_g      = (const float*)d_in[1];
    const float* ln_b      = (const float*)d_in[2];
    const float* in_proj_w = (const float*)d_in[3];
    const float* conv1d_w  = (const float*)d_in[4];
    const float* conv1d_b  = (const float*)d_in[5];
    const float* x_proj_w  = (const float*)d_in[6];
    const float* dt_proj_w = (const float*)d_in[7];
    const float* dt_proj_b = (const float*)d_in[8];
    const float* A_log     = (const float*)d_in[9];
    const float* D_f       = (const float*)d_in[10];
    const float* conv1db_w = (const float*)d_in[11];
    const float* conv1db_b = (const float*)d_in[12];
    const float* x_projb_w = (const float*)d_in[13];
    const float* dt_projb_w= (const float*)d_in[14];
    const float* dt_projb_b= (const float*)d_in[15];
    const float* Ab_log    = (const float*)d_in[16];
    const float* D_b       = (const float*)d_in[17];
    const float* out_proj_w= (const float*)d_in[18];
    const float* cp1_w     = (const float*)d_in[19];
    const float* cp1_b     = (const float*)d_in[20];
    const float* elk1_w    = (const float*)d_in[21];
    const float* elk1_b    = (const float*)d_in[22];
    const float* elk2_w    = (const float*)d_in[23];
    const float* elk2_b    = (const float*)d_in[24];
    const float* elk3_w    = (const float*)d_in[25];
    const float* elk3_b    = (const float*)d_in[26];
    const float* elk4_w    = (const float*)d_in[27];
    const float* elk4_b    = (const float*)d_in[28];
    const float* elk5_w    = (const float*)d_in[29];
    const float* elk5_b    = (const float*)d_in[30];
    const float* cp2_w     = (const float*)d_in[31];
    const float* cp2_b     = (const float*)d_in[32];
    const float* atten_w   = (const float*)d_in[33];
    const float* conv1_w   = (const float*)d_in[34];
    const float* conv2_w   = (const float*)d_in[35];
    const float* conv2_b   = (const float*)d_in[36];

    float* ws = (float*)d_ws;
    // workspace layout (floats)
    float* XI  = ws + 0;          // [64][L] (dead after k_conv_proj; reused as H1P)
    float* Z   = ws + 1048576;    // [L][64]
    float* UF  = ws + 2097152;    // [L][64]
    float* UB  = ws + 3145728;
    float* DLF = ws + 4194304;    // [L][64]
    float* DLB = ws + 5242880;
    float* BF  = ws + 6291456;    // [L][16]
    float* CF  = ws + 6553600;
    float* BB  = ws + 6815744;
    float* CB  = ws + 7077888;
    float* CHA = ws + 7340032;    // [2][NC][1024]
    float* CHB = ws + 7864320;
    float* HST = ws + 8388608;
    float* YF  = ws + 8912896;    // [L][64]
    float* YB  = ws + 9961472;    // [L][64]
    float* XM  = ws + 11010048;   // [32][L]
    float* H1  = ws + 11534336;   // [32][L]
    float* E4  = ws + 12058624;   // [64][L]
    float* H2  = ws + 13107200;
    float* H3  = ws + 13631488;
    float* ST  = ws + 14155776;   // stats1[64] stats2[64] stats3[64] pooled[64] attn[64]
    float* H1P = XI;              // padded H1: 32*PCH = 829440 floats < 1048576 (XI region)

    hipMemsetAsync(ST, 0, 256*sizeof(float), stream);

    // mamba branch (pre-scan) — uses XI
    k_ln_proj<<<dim3(L/64,4), 256, 0, stream>>>(x, ln_g, ln_b, in_proj_w, XI, Z);
    k_conv_proj<<<dim3(L/64,2), 256, 0, stream>>>(XI,
        conv1d_w, conv1d_b, x_proj_w, dt_proj_w, dt_proj_b,
        conv1db_w, conv1db_b, x_projb_w, dt_projb_w, dt_projb_b,
        UF, DLF, BF, CF, UB, DLB, BB, CB);
    k_scan1<<<dim3(NC,2), 1024, 0, stream>>>(DLF, BF, UF, DLB, BB, UB, A_log, Ab_log, CHA, CHB);
    k_scan_agg<<<2, 1024, 0, stream>>>(CHA, CHB, HST);
    k_scan2<<<dim3(NC,2), 1024, 0, stream>>>(DLF, BF, CF, UF, DLB, BB, CB, UB,
                                             A_log, Ab_log, D_f, D_b, HST, YF, YB);
    k_combine<<<dim3(L/64), 256, 0, stream>>>(YF, YB, Z, out_proj_w, XM);

    // conv3d branch — XI is now dead, reuse as padded H1
    k_conv1x1<<<dim3(32,8), 256, 0, stream>>>(x, cp1_w, cp1_b, H1, ST);
    hipMemsetAsync(H1P, 0, 32*PCH*sizeof(float), stream);
    k_norm_pad<<<dim3(32,8), 256, 0, stream>>>(H1, ST, H1P);
    k_elk<<<dim3(L/256,8), 256, 0, stream>>>(H1P, elk1_w, elk1_b, elk2_w, elk2_b,
                                             elk3_w, elk3_b, elk4_w, elk4_b, E4);
    k_elk5<<<dim3(32,16), 256, 0, stream>>>(E4, H1, elk5_w, elk5_b, H2, ST+64);
    k_norm<<<dim3(32,8), 256, 0, stream>>>(H2, ST+64);
    k_conv1x1<<<dim3(32,8), 256, 0, stream>>>(H2, cp2_w, cp2_b, H3, ST+128);
    k_norm<<<dim3(32,8), 256, 0, stream>>>(H3, ST+128);

    // fusion
    k_pool<<<dim3(64,8), 256, 0, stream>>>(H3, XM, ST+192);
    k_attn<<<1, 64, 0, stream>>>(ST+192, atten_w, ST+256);
    k_final<<<dim3(L/256,4), 256, 0, stream>>>(H3, XM, ST+256, conv1_w, conv2_w, conv2_b,
                                               (float*)d_out);
}